// Round 1
// baseline (22205.318 us; speedup 1.0000x reference)
//
#include <hip/hip_runtime.h>
#include <hip/hip_bf16.h>
#include <type_traits>

// Problem constants (fixed by setup_inputs).
#define TSTEPS 64
#define BATCH  256
#define NINPUT 1024
#define HID    2048
#define NZ     (4*HID)   // 8192
#define LNEPS  1e-5f

// ---------- small helpers ----------
__device__ __forceinline__ float toF(float v){ return v; }
__device__ __forceinline__ float toF(__hip_bfloat16 v){ return __bfloat162float(v); }
__device__ __forceinline__ void storeT(float* p, float v){ *p = v; }
__device__ __forceinline__ void storeT(__hip_bfloat16* p, float v){ *p = __float2bfloat16(v); }

// Block-wide sum over 256 threads (4 waves of 64). Returns result to all threads.
__device__ __forceinline__ float block_sum_256(float v){
  __shared__ float sm[4];
  #pragma unroll
  for (int o = 32; o; o >>= 1) v += __shfl_xor(v, o);
  if ((threadIdx.x & 63) == 0) sm[threadIdx.x >> 6] = v;
  __syncthreads();
  float r = sm[0] + sm[1] + sm[2] + sm[3];
  __syncthreads();   // protect sm reuse across back-to-back calls
  return r;
}

// ---------- tiled fp32 SGEMM: C(MxN) = A(MxK) @ B(KxN), optional per-row scale (1-mask) on A ----------
// All dims divide tile sizes exactly for our shapes (no bounds checks).
template<typename TC, int BM, int BN, int BK, int TM, int TN, int NT>
__global__ __launch_bounds__(NT)
void sgemm_rs(const float* __restrict__ A, const float* __restrict__ B,
              TC* __restrict__ C, int M, int N, int K,
              const float* __restrict__ maskRow)
{
  __shared__ float As[BK][BM];   // stored transposed for stride-1 microtile reads
  __shared__ float Bs[BK][BN];
  const int tid   = threadIdx.x;
  const int tileM = blockIdx.y * BM;
  const int tileN = blockIdx.x * BN;
  constexpr int TX = BN / TN;
  const int ty = tid / TX, tx = tid % TX;
  const int rm = ty * TM, rn = tx * TN;
  float acc[TM][TN] = {};

  constexpr int KQ  = BK / 4;
  constexpr int APT = (BM * BK / 4) / NT;   // float4 loads of A per thread
  constexpr int BPT = (BK * BN / 4) / NT;
  static_assert(APT * NT * 4 == BM * BK, "A tile must divide");
  static_assert(BPT * NT * 4 == BK * BN, "B tile must divide");

  for (int k0 = 0; k0 < K; k0 += BK) {
    __syncthreads();
    #pragma unroll
    for (int i = 0; i < APT; ++i) {
      int id = tid + i * NT;
      int r = id / KQ, kq = id % KQ;
      float4 v = *(const float4*)(A + (size_t)(tileM + r) * K + k0 + kq * 4);
      if (maskRow) {               // uniform branch; fold h *= (1-mask_t) into the A-load
        float s = 1.0f - maskRow[tileM + r];
        v.x *= s; v.y *= s; v.z *= s; v.w *= s;
      }
      As[kq*4+0][r] = v.x; As[kq*4+1][r] = v.y;
      As[kq*4+2][r] = v.z; As[kq*4+3][r] = v.w;
    }
    #pragma unroll
    for (int i = 0; i < BPT; ++i) {
      int id = tid + i * NT;
      int r = id / (BN/4), c4 = id % (BN/4);
      *(float4*)(&Bs[r][c4*4]) = *(const float4*)(B + (size_t)(k0 + r) * N + tileN + c4*4);
    }
    __syncthreads();
    #pragma unroll
    for (int kk = 0; kk < BK; ++kk) {
      float a[TM], bb[TN];
      #pragma unroll
      for (int i = 0; i < TM; i += 4) *(float4*)&a[i]  = *(const float4*)&As[kk][rm + i];
      #pragma unroll
      for (int j = 0; j < TN; j += 4) *(float4*)&bb[j] = *(const float4*)&Bs[kk][rn + j];
      #pragma unroll
      for (int i = 0; i < TM; ++i)
        #pragma unroll
        for (int j = 0; j < TN; ++j)
          acc[i][j] = fmaf(a[i], bb[j], acc[i][j]);
    }
  }
  #pragma unroll
  for (int i = 0; i < TM; ++i) {
    TC* cp = C + (size_t)(tileM + rm + i) * N + tileN + rn;
    if constexpr (std::is_same_v<TC, float>) {
      #pragma unroll
      for (int j = 0; j < TN; j += 4) *(float4*)(cp + j) = *(float4*)&acc[i][j];
    } else {
      #pragma unroll
      for (int j = 0; j < TN; ++j) storeT(cp + j, acc[i][j]);
    }
  }
}

// ---------- in-place row LayerNorm over width 8192: x = (x-mean)/sqrt(var+eps)*g + b ----------
template<typename TC>
__global__ __launch_bounds__(256)
void ln_rows8192(TC* __restrict__ xw, const float* __restrict__ g, const float* __restrict__ bv)
{
  TC* row = xw + (size_t)blockIdx.x * NZ;
  const int tid = threadIdx.x;
  float v[32];
  #pragma unroll
  for (int q = 0; q < 8; ++q) {
    int idx = q * 1024 + tid * 4;   // coalesced: lane stride 16B
    if constexpr (std::is_same_v<TC, float>) {
      float4 t = *(const float4*)(row + idx);
      v[q*4+0]=t.x; v[q*4+1]=t.y; v[q*4+2]=t.z; v[q*4+3]=t.w;
    } else {
      #pragma unroll
      for (int j = 0; j < 4; ++j) v[q*4+j] = toF(row[idx+j]);
    }
  }
  float s = 0.f;
  #pragma unroll
  for (int q = 0; q < 32; ++q) s += v[q];
  float mean = block_sum_256(s) * (1.0f / NZ);
  float sq = 0.f;
  #pragma unroll
  for (int q = 0; q < 32; ++q) { float d = v[q] - mean; sq += d * d; }  // two-pass: no cancellation
  float var = block_sum_256(sq) * (1.0f / NZ);
  float rs = 1.0f / sqrtf(var + LNEPS);
  #pragma unroll
  for (int q = 0; q < 8; ++q) {
    int idx = q * 1024 + tid * 4;
    float4 gg = *(const float4*)(g  + idx);
    float4 bb = *(const float4*)(bv + idx);
    float o0 = (v[q*4+0]-mean)*rs*gg.x + bb.x;
    float o1 = (v[q*4+1]-mean)*rs*gg.y + bb.y;
    float o2 = (v[q*4+2]-mean)*rs*gg.z + bb.z;
    float o3 = (v[q*4+3]-mean)*rs*gg.w + bb.w;
    if constexpr (std::is_same_v<TC, float>) {
      float4 t; t.x=o0; t.y=o1; t.z=o2; t.w=o3;
      *(float4*)(row + idx) = t;
    } else {
      storeT(row+idx+0,o0); storeT(row+idx+1,o1); storeT(row+idx+2,o2); storeT(row+idx+3,o3);
    }
  }
}

// ---------- fused per-step: LN(hw)+xln+b -> gates -> c,h update -> LN(c) -> outputs ----------
// One block per batch row. z staged in LDS (32 KB).
template<typename TC>
__global__ __launch_bounds__(256)
void lstm_step(const float* __restrict__ hw, const TC* __restrict__ xln,
               const float* __restrict__ bvec,
               const float* __restrict__ gh, const float* __restrict__ bh,
               const float* __restrict__ gc, const float* __restrict__ bc,
               const float* __restrict__ mask_t,
               float* __restrict__ cbuf, float* __restrict__ hbuf,
               float* __restrict__ hs_out)
{
  __shared__ float zb[NZ];
  const int r = blockIdx.x, tid = threadIdx.x;
  const float* hrow = hw  + (size_t)r * NZ;
  const TC*    xrow = xln + (size_t)r * NZ;

  float v[32];
  #pragma unroll
  for (int q = 0; q < 8; ++q) {
    float4 t = *(const float4*)(hrow + q*1024 + tid*4);
    v[q*4+0]=t.x; v[q*4+1]=t.y; v[q*4+2]=t.z; v[q*4+3]=t.w;
  }
  float s = 0.f;
  #pragma unroll
  for (int q = 0; q < 32; ++q) s += v[q];
  float mean = block_sum_256(s) * (1.0f / NZ);
  float sq = 0.f;
  #pragma unroll
  for (int q = 0; q < 32; ++q) { float d = v[q] - mean; sq += d * d; }
  float var = block_sum_256(sq) * (1.0f / NZ);
  float rs = 1.0f / sqrtf(var + LNEPS);

  #pragma unroll
  for (int q = 0; q < 8; ++q) {
    int idx = q*1024 + tid*4;
    float4 ghv = *(const float4*)(gh   + idx);
    float4 bhv = *(const float4*)(bh   + idx);
    float4 bbv = *(const float4*)(bvec + idx);
    float xr[4];
    if constexpr (std::is_same_v<TC, float>) {
      float4 t = *(const float4*)(xrow + idx);
      xr[0]=t.x; xr[1]=t.y; xr[2]=t.z; xr[3]=t.w;
    } else {
      #pragma unroll
      for (int j = 0; j < 4; ++j) xr[j] = toF(xrow[idx+j]);
    }
    const float* ghp = (const float*)&ghv;
    const float* bhp = (const float*)&bhv;
    const float* bbp = (const float*)&bbv;
    #pragma unroll
    for (int j = 0; j < 4; ++j)
      zb[idx+j] = (v[q*4+j] - mean) * rs * ghp[j] + bhp[j] + xr[j] + bbp[j];
  }
  __syncthreads();

  const float mval = 1.0f - mask_t[r];
  float cn[8], og[8];
  #pragma unroll
  for (int q = 0; q < 8; ++q) {
    int jj = tid + q * 256;
    float zi = zb[jj], zf = zb[jj+2048], zo = zb[jj+4096], zu = zb[jj+6144];
    float ig = 1.0f / (1.0f + expf(-zi));
    float fg = 1.0f / (1.0f + expf(-zf));
    og[q]    = 1.0f / (1.0f + expf(-zo));
    float ug = tanhf(zu);
    float cold = cbuf[(size_t)r*HID + jj] * mval;   // c *= (1-mask) folded here
    cn[q] = fg * cold + ig * ug;
  }
  float s2 = 0.f;
  #pragma unroll
  for (int q = 0; q < 8; ++q) s2 += cn[q];
  float meanc = block_sum_256(s2) * (1.0f / HID);
  float sq2 = 0.f;
  #pragma unroll
  for (int q = 0; q < 8; ++q) { float d = cn[q] - meanc; sq2 += d * d; }
  float varc = block_sum_256(sq2) * (1.0f / HID);
  float rsc = 1.0f / sqrtf(varc + LNEPS);
  #pragma unroll
  for (int q = 0; q < 8; ++q) {
    int jj = tid + q * 256;
    float hv = og[q] * tanhf((cn[q] - meanc) * rsc * gc[jj] + bc[jj]);
    cbuf[(size_t)r*HID + jj]   = cn[q];
    hbuf[(size_t)r*HID + jj]   = hv;
    hs_out[(size_t)r*HID + jj] = hv;
  }
}

// ---------- state init / final write ----------
__global__ void init_state(const float* __restrict__ ist, float* __restrict__ cb, float* __restrict__ hb){
  int idx = blockIdx.x * blockDim.x + threadIdx.x;
  if (idx >= BATCH * 2 * HID) return;
  int bq = idx / (2*HID), j = idx % (2*HID);
  float v = ist[(size_t)bq * TSTEPS * 2 * HID + j];   // reshape(B,T,2H)[:,0]
  if (j < HID) cb[(size_t)bq*HID + j] = v;
  else         hb[(size_t)bq*HID + j - HID] = v;
}

__global__ void write_state(const float* __restrict__ cb, const float* __restrict__ hb, float* __restrict__ so){
  int idx = blockIdx.x * blockDim.x + threadIdx.x;
  if (idx >= BATCH * 2 * HID) return;
  int bq = idx / (2*HID), j = idx % (2*HID);
  so[idx] = (j < HID) ? cb[(size_t)bq*HID + j] : hb[(size_t)bq*HID + j - HID];
}

// ---------- launch ----------
extern "C" void kernel_launch(void* const* d_in, const int* in_sizes, int n_in,
                              void* d_out, int out_size, void* d_ws, size_t ws_size,
                              hipStream_t stream)
{
  const float* x    = (const float*)d_in[0];
  const float* mask = (const float*)d_in[1];
  const float* ist  = (const float*)d_in[2];
  const float* wx   = (const float*)d_in[3];
  const float* wh   = (const float*)d_in[4];
  const float* bias = (const float*)d_in[5];
  const float* gx   = (const float*)d_in[6];
  const float* bx   = (const float*)d_in[7];
  const float* gh   = (const float*)d_in[8];
  const float* bh   = (const float*)d_in[9];
  const float* gc   = (const float*)d_in[10];
  const float* bc   = (const float*)d_in[11];
  float* out  = (float*)d_out;
  float* hs   = out;                                   // (T,B,H)
  float* sout = out + (size_t)TSTEPS * BATCH * HID;    // (B,2H)

  const size_t xln_elems  = (size_t)TSTEPS * BATCH * NZ;          // 134M
  const size_t rest_elems = (size_t)BATCH * NZ + 2*(size_t)BATCH*HID;
  const bool use_f32 = ws_size >= (xln_elems + rest_elems) * sizeof(float);   // needs ~524 MB

  float* restf;
  float* xlnf = nullptr; __hip_bfloat16* xlnb = nullptr;
  if (use_f32) { xlnf = (float*)d_ws; restf = xlnf + xln_elems; }
  else { xlnb = (__hip_bfloat16*)d_ws;
         restf = (float*)((char*)d_ws + xln_elems * sizeof(__hip_bfloat16)); }
  float* hw = restf;                       // (B, NZ)
  float* cb = hw + (size_t)BATCH * NZ;     // (B, H)
  float* hb = cb + (size_t)BATCH * HID;    // (B, H)

  { int n = BATCH * 2 * HID;
    init_state<<<(n + 255) / 256, 256, 0, stream>>>(ist, cb, hb); }

  // Precompute xln = LN(x @ wx)*gx + bx for all T*B rows (loop-invariant).
  dim3 g1(NZ / 128, (TSTEPS * BATCH) / 128);
  if (use_f32) {
    sgemm_rs<float,128,128,16,8,8,256><<<g1, 256, 0, stream>>>(x, wx, xlnf, TSTEPS*BATCH, NZ, NINPUT, nullptr);
    ln_rows8192<float><<<TSTEPS*BATCH, 256, 0, stream>>>(xlnf, gx, bx);
  } else {
    sgemm_rs<__hip_bfloat16,128,128,16,8,8,256><<<g1, 256, 0, stream>>>(x, wx, xlnb, TSTEPS*BATCH, NZ, NINPUT, nullptr);
    ln_rows8192<__hip_bfloat16><<<TSTEPS*BATCH, 256, 0, stream>>>(xlnb, gx, bx);
  }

  // Serial recurrence.
  dim3 g2(NZ / 128, BATCH / 64);
  for (int t = 0; t < TSTEPS; ++t) {
    sgemm_rs<float,64,128,16,8,8,128><<<g2, 128, 0, stream>>>(
        hb, wh, hw, BATCH, NZ, HID, mask + (size_t)t * BATCH);
    if (use_f32)
      lstm_step<float><<<BATCH, 256, 0, stream>>>(
          hw, xlnf + (size_t)t * BATCH * NZ, bias, gh, bh, gc, bc,
          mask + (size_t)t * BATCH, cb, hb, hs + (size_t)t * BATCH * HID);
    else
      lstm_step<__hip_bfloat16><<<BATCH, 256, 0, stream>>>(
          hw, xlnb + (size_t)t * BATCH * NZ, bias, gh, bh, gc, bc,
          mask + (size_t)t * BATCH, cb, hb, hs + (size_t)t * BATCH * HID);
  }

  { int n = BATCH * 2 * HID;
    write_state<<<(n + 255) / 256, 256, 0, stream>>>(cb, hb, sout); }
}

// Round 3
// 5502.359 us; speedup vs baseline: 4.0356x; 4.0356x over previous
//
#include <hip/hip_runtime.h>

// Problem constants (fixed by setup_inputs).
#define TSTEPS 64
#define BATCH  256
#define NINPUT 1024
#define HID    2048
#define NZ     (4*HID)   // 8192
#define LNEPS  1e-5f

typedef __attribute__((ext_vector_type(8))) short bf16x8;  // 8 bf16 = 4 VGPRs (guide §3)
typedef __attribute__((ext_vector_type(4))) float f32x4;
typedef unsigned short u16;
typedef unsigned int   u32;

__device__ __forceinline__ u16 f2bf(float f){            // RNE f32->bf16
  union { float f; u32 u; } v; v.f = f;
  u32 r = v.u + 0x7FFFu + ((v.u >> 16) & 1u);
  return (u16)(r >> 16);
}
__device__ __forceinline__ float bf2f(u16 h){
  union { u32 u; float f; } v; v.u = ((u32)h) << 16; return v.f;
}

// Block-wide sum over 256 threads (4 waves of 64). Returns result to all threads.
__device__ __forceinline__ float block_sum_256(float v){
  __shared__ float sm[4];
  #pragma unroll
  for (int o = 32; o; o >>= 1) v += __shfl_xor(v, o);
  if ((threadIdx.x & 63) == 0) sm[threadIdx.x >> 6] = v;
  __syncthreads();
  float r = sm[0] + sm[1] + sm[2] + sm[3];
  __syncthreads();
  return r;
}

// =======================================================================
// Split-bf16x3 MFMA GEMM:  Cpart[kz] = A_slice @ B_slice
//   A: [M][K] row-major, either f32 (split at stage time) or pre-split bf16 hi/lo
//   B: pre-split, TRANSPOSED bf16 [N][K] (hi/lo)
//   C: f32 partials, one [M][N] buffer per k-slice (blockIdx.z)
// Tile 128x128, BK=32 (one MFMA K), 256 threads = 4 waves in 2x2,
// wave tile 64x64 -> 4x4 frags of 16x16. 3 MFMAs per frag per K-step.
// LDS rows padded to 40 bf16 to break the 64B-stride bank conflict.
// =======================================================================
template<bool A_F32>
__global__ __launch_bounds__(256, 2)
void gemm_split(const float* __restrict__ Af,
                const u16* __restrict__ Ahi, const u16* __restrict__ Alo,
                const u16* __restrict__ Bhi, const u16* __restrict__ Blo,
                float* __restrict__ Cpart,
                int M, int N, int K, int Kslice,
                const float* __restrict__ maskRow)
{
  __shared__ u16 As[2][128][40];   // [hi/lo][m][k+pad]
  __shared__ u16 Bs[2][128][40];   // [hi/lo][n][k+pad]
  const int tid  = threadIdx.x;
  const int gn   = blockIdx.x * 128;
  const int gm   = blockIdx.y * 128;
  const int kz   = blockIdx.z;
  const int kbeg = kz * Kslice;
  const int w = tid >> 6, lane = tid & 63;
  const int lr = lane & 15, lg = lane >> 4;
  const int mw = (w >> 1) * 64, nw = (w & 1) * 64;

  f32x4 acc[4][4];
  #pragma unroll
  for (int i = 0; i < 4; ++i)
    #pragma unroll
    for (int j = 0; j < 4; ++j) acc[i][j] = f32x4{0.f, 0.f, 0.f, 0.f};

  for (int ks = 0; ks < Kslice; ks += 32) {
    const int kk = kbeg + ks;
    __syncthreads();
    // ---- stage A (hi/lo) ----
    if constexpr (A_F32) {
      #pragma unroll
      for (int p = 0; p < 4; ++p) {           // 128x32 f32 = 16KB, 4 f32/thread/pass
        int id  = tid + p * 256;
        int row = id >> 3, kq = (id & 7) * 4;
        float4 v = *(const float4*)(Af + (size_t)(gm + row) * K + kk + kq);
        ushort4 hv, lv;
        hv.x = f2bf(v.x); lv.x = f2bf(v.x - bf2f(hv.x));
        hv.y = f2bf(v.y); lv.y = f2bf(v.y - bf2f(hv.y));
        hv.z = f2bf(v.z); lv.z = f2bf(v.z - bf2f(hv.z));
        hv.w = f2bf(v.w); lv.w = f2bf(v.w - bf2f(hv.w));
        *(ushort4*)&As[0][row][kq] = hv;
        *(ushort4*)&As[1][row][kq] = lv;
      }
    } else {
      #pragma unroll
      for (int p = 0; p < 2; ++p) {           // 2x (16B hi + 16B lo)/thread
        int id  = tid + p * 256;
        int row = id >> 2, kc = (id & 3) * 8;
        uint4 vh = *(const uint4*)(Ahi + (size_t)(gm + row) * K + kk + kc);
        uint4 vl = *(const uint4*)(Alo + (size_t)(gm + row) * K + kk + kc);
        if (maskRow != nullptr && maskRow[gm + row] != 0.0f) {  // mask in {0,1}: exact zeroing
          vh = make_uint4(0u,0u,0u,0u); vl = make_uint4(0u,0u,0u,0u);
        }
        *(uint4*)&As[0][row][kc] = vh;
        *(uint4*)&As[1][row][kc] = vl;
      }
    }
    // ---- stage B (hi/lo), B^T layout so rows are n, contiguous k ----
    #pragma unroll
    for (int p = 0; p < 2; ++p) {
      int id  = tid + p * 256;
      int row = id >> 2, kc = (id & 3) * 8;
      *(uint4*)&Bs[0][row][kc] = *(const uint4*)(Bhi + (size_t)(gn + row) * K + kk + kc);
      *(uint4*)&Bs[1][row][kc] = *(const uint4*)(Blo + (size_t)(gn + row) * K + kk + kc);
    }
    __syncthreads();
    // ---- fragments: A lane holds A[lr][lg*8+j]; B lane holds B[lg*8+j][lr] (=Bs[lr][lg*8+j]) ----
    bf16x8 a0[4], a1[4], b0[4], b1[4];
    #pragma unroll
    for (int mf = 0; mf < 4; ++mf) {
      a0[mf] = *(const bf16x8*)&As[0][mw + mf*16 + lr][lg*8];
      a1[mf] = *(const bf16x8*)&As[1][mw + mf*16 + lr][lg*8];
    }
    #pragma unroll
    for (int nf = 0; nf < 4; ++nf) {
      b0[nf] = *(const bf16x8*)&Bs[0][nw + nf*16 + lr][lg*8];
      b1[nf] = *(const bf16x8*)&Bs[1][nw + nf*16 + lr][lg*8];
    }
    #pragma unroll
    for (int mf = 0; mf < 4; ++mf)
      #pragma unroll
      for (int nf = 0; nf < 4; ++nf) {
        acc[mf][nf] = __builtin_amdgcn_mfma_f32_16x16x32_bf16(a0[mf], b0[nf], acc[mf][nf], 0, 0, 0);
        acc[mf][nf] = __builtin_amdgcn_mfma_f32_16x16x32_bf16(a0[mf], b1[nf], acc[mf][nf], 0, 0, 0);
        acc[mf][nf] = __builtin_amdgcn_mfma_f32_16x16x32_bf16(a1[mf], b0[nf], acc[mf][nf], 0, 0, 0);
      }
  }
  // ---- write f32 partials; C/D layout: col=lane&15, row=(lane>>4)*4+j (m89-verified) ----
  float* Cb = Cpart + (size_t)kz * M * N;
  #pragma unroll
  for (int mf = 0; mf < 4; ++mf)
    #pragma unroll
    for (int nf = 0; nf < 4; ++nf) {
      int col = gn + nw + nf*16 + lr;
      #pragma unroll
      for (int j = 0; j < 4; ++j) {
        int row = gm + mw + mf*16 + lg*4 + j;
        Cb[(size_t)row * N + col] = acc[mf][nf][j];
      }
    }
}

// ---------- one-time weight transpose + hi/lo split: W[K][N] f32 -> T[N][K] bf16 hi/lo ----------
__global__ __launch_bounds__(256)
void transpose_split(const float* __restrict__ W, int K, int N,
                     u16* __restrict__ Thi, u16* __restrict__ Tlo)
{
  __shared__ float tile[64][65];
  const int tid = threadIdx.x;
  const int n0 = blockIdx.x * 64, k0 = blockIdx.y * 64;
  const int tx = tid & 15, ty = tid >> 4;
  #pragma unroll
  for (int i = 0; i < 4; ++i) {
    float4 v = *(const float4*)(W + (size_t)(k0 + ty + i*16) * N + n0 + tx*4);
    tile[ty + i*16][tx*4+0] = v.x;
    tile[ty + i*16][tx*4+1] = v.y;
    tile[ty + i*16][tx*4+2] = v.z;
    tile[ty + i*16][tx*4+3] = v.w;
  }
  __syncthreads();
  #pragma unroll
  for (int i = 0; i < 4; ++i) {
    int nl = ty + i*16;
    float a0 = tile[tx*4+0][nl], a1 = tile[tx*4+1][nl],
          a2 = tile[tx*4+2][nl], a3 = tile[tx*4+3][nl];
    ushort4 hv, lv;
    hv.x = f2bf(a0); lv.x = f2bf(a0 - bf2f(hv.x));
    hv.y = f2bf(a1); lv.y = f2bf(a1 - bf2f(hv.y));
    hv.z = f2bf(a2); lv.z = f2bf(a2 - bf2f(hv.z));
    hv.w = f2bf(a3); lv.w = f2bf(a3 - bf2f(hv.w));
    *(ushort4*)(Thi + (size_t)(n0 + nl) * K + k0 + tx*4) = hv;
    *(ushort4*)(Tlo + (size_t)(n0 + nl) * K + k0 + tx*4) = lv;
  }
}

// ---------- fused per-step: sum partials, LN(h@wh), LN(x@wx), gates, cell-LN, outputs ----------
__global__ __launch_bounds__(256)
void lstm_step2(const float* __restrict__ hwp, const float* __restrict__ xwp,  // [4][B][NZ]
                const float* __restrict__ bvec,
                const float* __restrict__ gh, const float* __restrict__ bh,
                const float* __restrict__ gx, const float* __restrict__ bx,
                const float* __restrict__ gc, const float* __restrict__ bc,
                const float* __restrict__ mask_t,
                float* __restrict__ cbuf, u16* __restrict__ hbhi, u16* __restrict__ hblo,
                float* __restrict__ hs_out)
{
  __shared__ float zb[NZ];  // 32 KB
  const int r = blockIdx.x, tid = threadIdx.x;
  float v[32];

  // ---- h-path: sum 4 split-K partials, LN, *gh+bh -> zb ----
  #pragma unroll
  for (int q = 0; q < 8; ++q) {
    int idx = q*1024 + tid*4;
    float4 s0 = *(const float4*)(hwp + ((size_t)0*BATCH + r)*NZ + idx);
    float4 s1 = *(const float4*)(hwp + ((size_t)1*BATCH + r)*NZ + idx);
    float4 s2 = *(const float4*)(hwp + ((size_t)2*BATCH + r)*NZ + idx);
    float4 s3 = *(const float4*)(hwp + ((size_t)3*BATCH + r)*NZ + idx);
    v[q*4+0] = (s0.x+s1.x)+(s2.x+s3.x);
    v[q*4+1] = (s0.y+s1.y)+(s2.y+s3.y);
    v[q*4+2] = (s0.z+s1.z)+(s2.z+s3.z);
    v[q*4+3] = (s0.w+s1.w)+(s2.w+s3.w);
  }
  float s = 0.f;
  #pragma unroll
  for (int q = 0; q < 32; ++q) s += v[q];
  float mean = block_sum_256(s) * (1.0f / NZ);
  float sq = 0.f;
  #pragma unroll
  for (int q = 0; q < 32; ++q) { float d = v[q] - mean; sq += d * d; }
  float rs = 1.0f / sqrtf(block_sum_256(sq) * (1.0f / NZ) + LNEPS);
  #pragma unroll
  for (int q = 0; q < 8; ++q) {
    int idx = q*1024 + tid*4;
    float4 g4 = *(const float4*)(gh + idx);
    float4 b4 = *(const float4*)(bh + idx);
    float4 o;
    o.x = (v[q*4+0]-mean)*rs*g4.x + b4.x;
    o.y = (v[q*4+1]-mean)*rs*g4.y + b4.y;
    o.z = (v[q*4+2]-mean)*rs*g4.z + b4.z;
    o.w = (v[q*4+3]-mean)*rs*g4.w + b4.w;
    *(float4*)&zb[idx] = o;
  }
  // ---- x-path: same, accumulate into zb together with bias b ----
  #pragma unroll
  for (int q = 0; q < 8; ++q) {
    int idx = q*1024 + tid*4;
    float4 s0 = *(const float4*)(xwp + ((size_t)0*BATCH + r)*NZ + idx);
    float4 s1 = *(const float4*)(xwp + ((size_t)1*BATCH + r)*NZ + idx);
    float4 s2 = *(const float4*)(xwp + ((size_t)2*BATCH + r)*NZ + idx);
    float4 s3 = *(const float4*)(xwp + ((size_t)3*BATCH + r)*NZ + idx);
    v[q*4+0] = (s0.x+s1.x)+(s2.x+s3.x);
    v[q*4+1] = (s0.y+s1.y)+(s2.y+s3.y);
    v[q*4+2] = (s0.z+s1.z)+(s2.z+s3.z);
    v[q*4+3] = (s0.w+s1.w)+(s2.w+s3.w);
  }
  float s2s = 0.f;
  #pragma unroll
  for (int q = 0; q < 32; ++q) s2s += v[q];
  float meanx = block_sum_256(s2s) * (1.0f / NZ);
  float sqx = 0.f;
  #pragma unroll
  for (int q = 0; q < 32; ++q) { float d = v[q] - meanx; sqx += d * d; }
  float rsx = 1.0f / sqrtf(block_sum_256(sqx) * (1.0f / NZ) + LNEPS);
  #pragma unroll
  for (int q = 0; q < 8; ++q) {
    int idx = q*1024 + tid*4;
    float4 g4 = *(const float4*)(gx + idx);
    float4 b4 = *(const float4*)(bx + idx);
    float4 bb = *(const float4*)(bvec + idx);
    float4 o = *(const float4*)&zb[idx];
    o.x += (v[q*4+0]-meanx)*rsx*g4.x + b4.x + bb.x;
    o.y += (v[q*4+1]-meanx)*rsx*g4.y + b4.y + bb.y;
    o.z += (v[q*4+2]-meanx)*rsx*g4.z + b4.z + bb.z;
    o.w += (v[q*4+3]-meanx)*rsx*g4.w + b4.w + bb.w;
    *(float4*)&zb[idx] = o;
  }
  __syncthreads();

  // ---- gates / cell update / cell-LN ----
  const float mval = 1.0f - mask_t[r];   // mask in {0,1}: exact
  float cn[8], og[8];
  #pragma unroll
  for (int q = 0; q < 8; ++q) {
    int jj = tid + q * 256;
    float zi = zb[jj], zf = zb[jj+2048], zo = zb[jj+4096], zu = zb[jj+6144];
    float ig = 1.0f / (1.0f + expf(-zi));
    float fg = 1.0f / (1.0f + expf(-zf));
    og[q]    = 1.0f / (1.0f + expf(-zo));
    float ug = tanhf(zu);
    float cold = cbuf[(size_t)r*HID + jj] * mval;
    cn[q] = fg * cold + ig * ug;
  }
  float sc = 0.f;
  #pragma unroll
  for (int q = 0; q < 8; ++q) sc += cn[q];
  float meanc = block_sum_256(sc) * (1.0f / HID);
  float sqc = 0.f;
  #pragma unroll
  for (int q = 0; q < 8; ++q) { float d = cn[q] - meanc; sqc += d * d; }
  float rsc = 1.0f / sqrtf(block_sum_256(sqc) * (1.0f / HID) + LNEPS);
  #pragma unroll
  for (int q = 0; q < 8; ++q) {
    int jj = tid + q * 256;
    float hv = og[q] * tanhf((cn[q] - meanc) * rsc * gc[jj] + bc[jj]);
    cbuf[(size_t)r*HID + jj]   = cn[q];
    u16 hi = f2bf(hv);
    hbhi[(size_t)r*HID + jj]   = hi;
    hblo[(size_t)r*HID + jj]   = f2bf(hv - bf2f(hi));
    hs_out[(size_t)r*HID + jj] = hv;
  }
}

// ---------- state init / final write ----------
__global__ void init_state2(const float* __restrict__ ist, float* __restrict__ cb,
                            u16* __restrict__ hbhi, u16* __restrict__ hblo){
  int idx = blockIdx.x * blockDim.x + threadIdx.x;
  if (idx >= BATCH * 2 * HID) return;
  int bq = idx / (2*HID), j = idx % (2*HID);
  float vv = ist[(size_t)bq * TSTEPS * 2 * HID + j];   // reshape(B,T,2H)[:,0]
  if (j < HID) cb[(size_t)bq*HID + j] = vv;
  else {
    u16 hi = f2bf(vv);
    hbhi[(size_t)bq*HID + j - HID] = hi;
    hblo[(size_t)bq*HID + j - HID] = f2bf(vv - bf2f(hi));
  }
}

__global__ void write_state2(const float* __restrict__ cb, const u16* __restrict__ hbhi,
                             const u16* __restrict__ hblo, float* __restrict__ so){
  int idx = blockIdx.x * blockDim.x + threadIdx.x;
  if (idx >= BATCH * 2 * HID) return;
  int bq = idx / (2*HID), j = idx % (2*HID);
  so[idx] = (j < HID) ? cb[(size_t)bq*HID + j]
                      : (bf2f(hbhi[(size_t)bq*HID + j - HID]) + bf2f(hblo[(size_t)bq*HID + j - HID]));
}

// ---------- launch ----------
extern "C" void kernel_launch(void* const* d_in, const int* in_sizes, int n_in,
                              void* d_out, int out_size, void* d_ws, size_t ws_size,
                              hipStream_t stream)
{
  const float* x    = (const float*)d_in[0];
  const float* mask = (const float*)d_in[1];
  const float* ist  = (const float*)d_in[2];
  const float* wx   = (const float*)d_in[3];
  const float* wh   = (const float*)d_in[4];
  const float* bias = (const float*)d_in[5];
  const float* gx   = (const float*)d_in[6];
  const float* bx   = (const float*)d_in[7];
  const float* gh   = (const float*)d_in[8];
  const float* bh   = (const float*)d_in[9];
  const float* gc   = (const float*)d_in[10];
  const float* bc   = (const float*)d_in[11];
  float* out  = (float*)d_out;
  float* hs   = out;                                   // (T,B,H)
  float* sout = out + (size_t)TSTEPS * BATCH * HID;    // (B,2H)

  // Workspace carve (~164 MB total; ws >= 524 MB proven by R1's f32 path).
  char* p = (char*)d_ws;
  auto carve = [&](size_t bytes)->char* {
    char* q = p; p += (bytes + 255) & ~(size_t)255; return q;
  };
  u16*   whT_hi = (u16*)  carve((size_t)NZ * HID    * 2);   // [8192][2048]
  u16*   whT_lo = (u16*)  carve((size_t)NZ * HID    * 2);
  u16*   wxT_hi = (u16*)  carve((size_t)NZ * NINPUT * 2);   // [8192][1024]
  u16*   wxT_lo = (u16*)  carve((size_t)NZ * NINPUT * 2);
  float* hwp    = (float*)carve((size_t)4 * BATCH * NZ * 4);
  float* xwp    = (float*)carve((size_t)4 * BATCH * NZ * 4);
  float* cb     = (float*)carve((size_t)BATCH * HID * 4);
  u16*   hbhi   = (u16*)  carve((size_t)BATCH * HID * 2);
  u16*   hblo   = (u16*)  carve((size_t)BATCH * HID * 2);

  { int n = BATCH * 2 * HID;
    init_state2<<<(n + 255) / 256, 256, 0, stream>>>(ist, cb, hbhi, hblo); }

  // One-time weight transpose + split.
  transpose_split<<<dim3(NZ/64, HID/64),    256, 0, stream>>>(wh, HID,    NZ, whT_hi, whT_lo);
  transpose_split<<<dim3(NZ/64, NINPUT/64), 256, 0, stream>>>(wx, NINPUT, NZ, wxT_hi, wxT_lo);

  // Serial recurrence: two split-bf16x3 MFMA GEMMs + fused LN/gate step per t.
  const dim3 gg(NZ/128, BATCH/128, 4);   // (64, 2, 4): N-tiles, M-tiles, split-K
  for (int t = 0; t < TSTEPS; ++t) {
    gemm_split<false><<<gg, 256, 0, stream>>>(
        nullptr, hbhi, hblo, whT_hi, whT_lo, hwp,
        BATCH, NZ, HID, HID/4, mask + (size_t)t * BATCH);
    gemm_split<true><<<gg, 256, 0, stream>>>(
        x + (size_t)t * BATCH * NINPUT, nullptr, nullptr, wxT_hi, wxT_lo, xwp,
        BATCH, NZ, NINPUT, NINPUT/4, nullptr);
    lstm_step2<<<BATCH, 256, 0, stream>>>(
        hwp, xwp, bias, gh, bh, gx, bx, gc, bc,
        mask + (size_t)t * BATCH, cb, hbhi, hblo,
        hs + (size_t)t * BATCH * HID);
  }

  { int n = BATCH * 2 * HID;
    write_state2<<<(n + 255) / 256, 256, 0, stream>>>(cb, hbhi, hblo, sout); }
}